// Round 7
// baseline (214.755 us; speedup 1.0000x reference)
//
#include <hip/hip_runtime.h>
#include <hip/hip_bf16.h>
#include <cstdint>

typedef unsigned int uint32;
typedef unsigned short ushort;
typedef __attribute__((ext_vector_type(8))) short short8;   // 8 bf16 (4 VGPRs)
typedef __attribute__((ext_vector_type(4))) float f32x4;    // MFMA C/D

#define EPB 4096      // edges per block in hist/partition kernels
#define SLACK 3840    // max padding per 256-node bucket (256*15)

__device__ inline ushort bf16r(float f) {
    uint32 u = __float_as_uint(f);
    u += 0x7fff + ((u >> 16) & 1);
    return (ushort)(u >> 16);
}
__device__ inline uint32 pack_bf16(float a, float b) {
    return (uint32)bf16r(a) | ((uint32)bf16r(b) << 16);
}
__device__ inline float bf_lo(uint32 w) { return __uint_as_float(w << 16); }
__device__ inline float bf_hi(uint32 w) { return __uint_as_float(w & 0xffff0000u); }

// ---------------- K1: per-block dense bucket hist + W-prep + dummy-row zero ----------------
// bucket = dst >> 8 (256-node windows, NB<=256)

__global__ __launch_bounds__(256) void k_bhist_prep(
        const int* __restrict__ dstv, int* __restrict__ hglob, int e, int nbE,
        const float* __restrict__ W1, const float* __restrict__ W2, const float* __restrict__ W3,
        ushort* __restrict__ Wt1, ushort* __restrict__ Wt2, ushort* __restrict__ Wt3,
        ushort* __restrict__ hsb, ushort* __restrict__ hs3, int n) {
    __shared__ int h[256];
    int bid = blockIdx.x, t = threadIdx.x;
    if (bid < nbE) {
        h[t] = 0;
        __syncthreads();
        int b0 = bid * EPB;
#pragma unroll
        for (int i = 0; i < EPB / 256; ++i) {
            int idx = b0 + i * 256 + t;
            if (idx < e) atomicAdd(&h[dstv[idx] >> 8], 1);
        }
        __syncthreads();
        hglob[bid * 256 + t] = h[t];
    } else {
        int wb = bid - nbE;
        if (wb < 3) {
            const float* W = wb == 0 ? W1 : (wb == 1 ? W2 : W3);
            ushort* Wt = wb == 0 ? Wt1 : (wb == 1 ? Wt2 : Wt3);
            int F = wb == 2 ? 64 : 128;
            for (int i = t; i < 128 * F; i += 256) {
                int k = i / F, c = i % F;
                Wt[c * 128 + k] = bf16r(W[i]);
            }
        } else {
            // zero dummy gather rows (node index n)
            if (t < 128) hsb[(size_t)n * 128 + t] = 0;
            if (t < 64)  hs3[(size_t)n * 64 + t] = 0;
        }
    }
}

// ---------------- K2: bucket scan (coalesced column sums) ----------------

__global__ __launch_bounds__(256) void k_bscan(const int* __restrict__ hglob, int nbE,
                                               int* __restrict__ bpre, int* __restrict__ bcur,
                                               int nb, int e) {
    __shared__ int s[256];
    int t = threadIdx.x;
    int v = 0;
    for (int b = 0; b < nbE; ++b) v += hglob[b * 256 + t];
    s[t] = v;
    __syncthreads();
    for (int off = 1; off < 256; off <<= 1) {
        int a = (t >= off) ? s[t - off] : 0;
        __syncthreads();
        s[t] += a;
        __syncthreads();
    }
    if (t < nb) { bpre[t] = s[t] - v; bcur[t] = s[t] - v; }
    if (t == 0) bpre[nb] = e;
}

// ---------------- K3: partition edges into bucket-contiguous pair array ----------------

__global__ __launch_bounds__(256) void k_partition(const int* __restrict__ srcv,
                                                   const int* __restrict__ dstv,
                                                   int* __restrict__ bcur,
                                                   uint2* __restrict__ pairs, int e) {
    __shared__ int h[256], base[256], cur[256];
    int t = threadIdx.x;
    h[t] = 0; cur[t] = 0;
    __syncthreads();
    int s[EPB / 256], d[EPB / 256];
    int b0 = blockIdx.x * EPB;
#pragma unroll
    for (int i = 0; i < EPB / 256; ++i) {
        int idx = b0 + i * 256 + t;
        if (idx < e) {
            s[i] = srcv[idx]; d[i] = dstv[idx];
            atomicAdd(&h[d[i] >> 8], 1);
        } else d[i] = -1;
    }
    __syncthreads();
    if (h[t]) base[t] = atomicAdd(&bcur[t], h[t]);
    __syncthreads();
#pragma unroll
    for (int i = 0; i < EPB / 256; ++i) {
        if (d[i] >= 0) {
            int b = d[i] >> 8;
            int sl = atomicAdd(&cur[b], 1);
            pairs[base[b] + sl] = make_uint2((unsigned)s[i], (unsigned)d[i]);
        }
    }
}

// ---------------- K4: per-bucket finish — padded CSR (pad to x16 with dummy node n) ----------------

__global__ __launch_bounds__(256) void k_bfinish(const uint2* __restrict__ pairs,
                                                 const int* __restrict__ bpre,
                                                 int2* __restrict__ rps, float* __restrict__ dis,
                                                 int* __restrict__ col, int n) {
    __shared__ int c[256], sc[256], cur[256];
    int t = threadIdx.x;
    c[t] = 0; cur[t] = 0;
    __syncthreads();
    int wb = blockIdx.x << 8;
    int e0 = bpre[blockIdx.x], e1 = bpre[blockIdx.x + 1];
    for (int i = e0 + t; i < e1; i += 256) atomicAdd(&c[(int)pairs[i].y - wb], 1);
    __syncthreads();
    int own = c[t];
    int pad = (own + 15) & ~15;
    sc[t] = pad;
    __syncthreads();
    for (int off = 1; off < 256; off <<= 1) {
        int a = (t >= off) ? sc[t - off] : 0;
        __syncthreads();
        sc[t] += a;
        __syncthreads();
    }
    int start = bpre[blockIdx.x] + blockIdx.x * SLACK + sc[t] - pad;
    __syncthreads();
    sc[t] = start;
    int v = wb + t;
    if (v < n) {
        rps[v] = make_int2(start, start + pad);
        dis[v] = rsqrtf((float)(own + 1));
    }
    __syncthreads();
    for (int i = e0 + t; i < e1; i += 256) {
        uint2 p = pairs[i];
        int bl = (int)p.y - wb;
        int sl = atomicAdd(&cur[bl], 1);
        col[sc[bl] + sl] = (int)p.x;
    }
    __syncthreads();
    for (int i = own; i < pad; ++i) col[start + i] = n;   // dummy edges -> zero row
}

// ------- MFMA GEMM: Yb[r][c] = bf16( dis[r] * sum_k X[r][k] * W[k][c] ) -------

template <int FOUT, bool BF16IN>
__global__ __launch_bounds__(256) void k_gemm_mfma(
        const void* __restrict__ Xv, const ushort* __restrict__ Wt,
        const float* __restrict__ dis, ushort* __restrict__ Yb, int n) {
    constexpr int CT = FOUT / 16;
    int lane = threadIdx.x & 63;
    int wv = threadIdx.x >> 6;
    int r16 = lane & 15, kg = lane >> 4;
    int rowA = blockIdx.x * 64 + wv * 16 + r16;
    int ra = min(rowA, n - 1);
    short8 afr[4];
    if (BF16IN) {
        const ushort* Xb = (const ushort*)Xv;
#pragma unroll
        for (int ks = 0; ks < 4; ++ks)
            afr[ks] = *(const short8*)(Xb + (size_t)ra * 128 + ks * 32 + kg * 8);
    } else {
        const float* Xf = (const float*)Xv;
#pragma unroll
        for (int ks = 0; ks < 4; ++ks) {
            const float* p = Xf + (size_t)ra * 128 + ks * 32 + kg * 8;
            float4 f0 = *(const float4*)p;
            float4 f1 = *(const float4*)(p + 4);
            short8 a;
            a[0] = (short)bf16r(f0.x); a[1] = (short)bf16r(f0.y);
            a[2] = (short)bf16r(f0.z); a[3] = (short)bf16r(f0.w);
            a[4] = (short)bf16r(f1.x); a[5] = (short)bf16r(f1.y);
            a[6] = (short)bf16r(f1.z); a[7] = (short)bf16r(f1.w);
            afr[ks] = a;
        }
    }
    f32x4 acc[CT];
#pragma unroll
    for (int c = 0; c < CT; ++c) acc[c] = (f32x4){0.f, 0.f, 0.f, 0.f};
#pragma unroll
    for (int ks = 0; ks < 4; ++ks) {
#pragma unroll
        for (int c = 0; c < CT; ++c) {
            short8 b = *(const short8*)(Wt + (c * 16 + r16) * 128 + ks * 32 + kg * 8);
            acc[c] = __builtin_amdgcn_mfma_f32_16x16x32_bf16(afr[ks], b, acc[c], 0, 0, 0);
        }
    }
    int rbase = blockIdx.x * 64 + wv * 16 + kg * 4;
#pragma unroll
    for (int j = 0; j < 4; ++j) {
        int row = rbase + j;
        if (row < n) {
            float d = dis[row];
#pragma unroll
            for (int c = 0; c < CT; ++c)
                Yb[(size_t)row * FOUT + c * 16 + r16] = bf16r(acc[c][j] * d);
        }
    }
}

// ---------------- aggregation: branch-free 16-wide padded gathers ----------------
// outb[v] = bf16( relu( dis[v] * (hs[v] + sum_nbr hs[u]) + b ) )

__global__ __launch_bounds__(256) void k_agg_relu128(
        const uint32* __restrict__ hb, const int2* __restrict__ rps,
        const int* __restrict__ col, const float* __restrict__ dis,
        const float* __restrict__ bias, uint32* __restrict__ outb, int n) {
    int wid = threadIdx.x >> 6;
    int lane = threadIdx.x & 63;
    int v = blockIdx.x * 4 + wid;
    if (v >= n) return;
    uint32 mv = hb[(size_t)v * 64 + lane];
    float ax = bf_lo(mv), ay = bf_hi(mv);
    int2 se = rps[v];
    int s = __builtin_amdgcn_readfirstlane(se.x);
    int e = __builtin_amdgcn_readfirstlane(se.y);
    for (int k = s; k < e; k += 16) {
        uint32 m[16];
#pragma unroll
        for (int j = 0; j < 16; ++j) {
            int u = col[k + j];
            m[j] = hb[(size_t)u * 64 + lane];
        }
#pragma unroll
        for (int j = 0; j < 16; ++j) { ax += bf_lo(m[j]); ay += bf_hi(m[j]); }
    }
    float d = dis[v];
    float2 b = ((const float2*)bias)[lane];
    float ox = fmaxf(d * ax + b.x, 0.f);
    float oy = fmaxf(d * ay + b.y, 0.f);
    outb[(size_t)v * 64 + lane] = pack_bf16(ox, oy);
}

// final layer: F=64 bf16 rows, fused bias + log_softmax (fp32 out)
__global__ __launch_bounds__(256) void k_agg_lsm64(
        const ushort* __restrict__ hb, const int2* __restrict__ rps,
        const int* __restrict__ col, const float* __restrict__ dis,
        const float* __restrict__ bias, float* __restrict__ out, int n) {
    int wid = threadIdx.x >> 6;
    int lane = threadIdx.x & 63;
    int v = blockIdx.x * 4 + wid;
    if (v >= n) return;
    float acc = __uint_as_float((uint32)hb[(size_t)v * 64 + lane] << 16);
    int2 se = rps[v];
    int s = __builtin_amdgcn_readfirstlane(se.x);
    int e = __builtin_amdgcn_readfirstlane(se.y);
    for (int k = s; k < e; k += 16) {
        ushort m[16];
#pragma unroll
        for (int j = 0; j < 16; ++j) m[j] = hb[(size_t)col[k + j] * 64 + lane];
#pragma unroll
        for (int j = 0; j < 16; ++j) acc += __uint_as_float((uint32)m[j] << 16);
    }
    float val = dis[v] * acc + bias[lane];
    float m = val;
    for (int off = 32; off; off >>= 1) m = fmaxf(m, __shfl_xor(m, off, 64));
    float ex = expf(val - m);
    float ss = ex;
    for (int off = 32; off; off >>= 1) ss += __shfl_xor(ss, off, 64);
    out[(size_t)v * 64 + lane] = val - m - logf(ss);
}

// ---------------- launch ----------------

extern "C" void kernel_launch(void* const* d_in, const int* in_sizes, int n_in,
                              void* d_out, int out_size, void* d_ws, size_t ws_size,
                              hipStream_t stream) {
    const float* x  = (const float*)d_in[0];
    const float* W1 = (const float*)d_in[1];
    const float* b1 = (const float*)d_in[2];
    const float* W2 = (const float*)d_in[3];
    const float* b2 = (const float*)d_in[4];
    const float* W3 = (const float*)d_in[5];
    const float* b3 = (const float*)d_in[6];
    const int*   ei = (const int*)d_in[7];

    const int N = in_sizes[0] / 128;
    const int E = in_sizes[7] / 2;
    const int* srcv = ei;
    const int* dstv = ei + E;
    const int NB  = (N + 255) >> 8;          // 256-node buckets
    const int nbE = (E + EPB - 1) / EPB;

    char* ws = (char*)d_ws;
    size_t off = 0;
    auto alloc = [&](size_t bytes) -> void* {
        void* p = ws + off;
        off += (bytes + 255) & ~(size_t)255;
        return p;
    };
    float*  dis   = (float*)alloc((size_t)N * 4);
    int2*   rps   = (int2*)alloc((size_t)N * 8);
    int*    col   = (int*)alloc(((size_t)E + (size_t)NB * SLACK + 16) * 4);
    int*    hglob = (int*)alloc((size_t)nbE * 256 * 4);
    int*    bpre  = (int*)alloc((size_t)(NB + 1) * 4);
    int*    bcur  = (int*)alloc((size_t)(NB + 1) * 4);
    uint2*  pairs = (uint2*)alloc((size_t)E * 8);
    ushort* Wt1   = (ushort*)alloc(128 * 128 * 2);
    ushort* Wt2   = (ushort*)alloc(128 * 128 * 2);
    ushort* Wt3   = (ushort*)alloc(64 * 128 * 2);
    ushort* hsb   = (ushort*)alloc((size_t)(N + 1) * 128 * 2);  // GEMM1/2 out, gather src (+dummy row)
    ushort* hbX   = (ushort*)alloc((size_t)N * 128 * 2);        // agg out / GEMM in
    ushort* hs3   = (ushort*)alloc((size_t)(N + 1) * 64 * 2);   // GEMM3 out (+dummy row)
    float*  outp  = (float*)d_out;

    // --- CSR build (padded) + weight prep ---
    k_bhist_prep<<<nbE + 4, 256, 0, stream>>>(dstv, hglob, E, nbE,
                                              W1, W2, W3, Wt1, Wt2, Wt3, hsb, hs3, N);
    k_bscan<<<1, 256, 0, stream>>>(hglob, nbE, bpre, bcur, NB, E);
    k_partition<<<nbE, 256, 0, stream>>>(srcv, dstv, bcur, pairs, E);
    k_bfinish<<<NB, 256, 0, stream>>>(pairs, bpre, rps, dis, col, N);

    // --- 3 GCN layers ---
    int gblk = (N + 63) / 64;
    int ablk = (N + 3) / 4;
    k_gemm_mfma<128, false><<<gblk, 256, 0, stream>>>(x, Wt1, dis, hsb, N);
    k_agg_relu128<<<ablk, 256, 0, stream>>>((const uint32*)hsb, rps, col, dis, b1, (uint32*)hbX, N);
    k_gemm_mfma<128, true><<<gblk, 256, 0, stream>>>(hbX, Wt2, dis, hsb, N);
    k_agg_relu128<<<ablk, 256, 0, stream>>>((const uint32*)hsb, rps, col, dis, b2, (uint32*)hbX, N);
    k_gemm_mfma<64, true><<<gblk, 256, 0, stream>>>(hbX, Wt3, dis, hs3, N);
    k_agg_lsm64<<<ablk, 256, 0, stream>>>(hs3, rps, col, dis, b3, outp, N);
}